// Round 1
// baseline (242.429 us; speedup 1.0000x reference)
//
#include <hip/hip_runtime.h>
#include <math.h>

#define KTOP 200
#define NPART 32
#define EQ_CAP 1024
#define BLOCK 256

// d2 exactly as numpy: ((dx*dx + dy*dy) + dz*dz), no fma contraction
__device__ __forceinline__ float d2_ref(float ax, float ay, float az,
                                        float bx, float by, float bz) {
    float dx = __fsub_rn(ax, bx), dy = __fsub_rn(ay, by), dz = __fsub_rn(az, bz);
    return __fadd_rn(__fadd_rn(__fmul_rn(dx, dx), __fmul_rn(dy, dy)), __fmul_rn(dz, dz));
}

// shape-context bin of rel = p_j - q0, mirroring the reference f32 math
__device__ __forceinline__ int compute_bin(float rx, float ry, float rz) {
    const float TWO_PI_F = (float)6.283185307179586;
    const float PI_F     = (float)3.141592653589793;
    const float XY_W     = (float)(6.283185307179586 / 4.0);  // 2pi/NBINS_XY
    const float ZY_W     = (float)(3.141592653589793 / 4.0);  // pi/NBINS_ZY

    float d2 = __fadd_rn(__fadd_rn(__fmul_rn(rx, rx), __fmul_rn(ry, ry)), __fmul_rn(rz, rz));
    float D  = sqrtf(__fadd_rn(d2, 1e-7f));
    float dist_bin;
    if (D >= 4.0f)      dist_bin = 1.0f;
    else if (D >= 1.0f) dist_bin = 0.0f;
    else                return -1;

    float axy = fmodf(atan2f(ry, rx) + TWO_PI_F, TWO_PI_F);
    float azy = fmodf(atan2f(ry, rz) + TWO_PI_F, PI_F);
    float xyb = floorf(__fdiv_rn(axy, XY_W));
    float zyb = floorf(__fdiv_rn(azy, ZY_W));
    if (!(xyb >= 0.0f && zyb >= 0.0f)) return -1;
    float ab  = xyb * 4.0f + zyb;          // NBINS_ZY = 4
    int bin = (int)(dist_bin * 16.0f + ab);
    return bin;   // may be >=32 in edge cases; caller ignores those (ref counts only 0..31)
}

__global__ __launch_bounds__(BLOCK)
void shape_context_kernel(const float* __restrict__ veh,
                          const float* __restrict__ fus,
                          float* __restrict__ out,
                          int nfus) {
    const int b   = blockIdx.x;
    const int tid = threadIdx.x;

    __shared__ unsigned int hist[256];
    __shared__ unsigned int hist32[NPART];
    __shared__ unsigned long long s_minPacked;
    __shared__ unsigned int s_rem;
    __shared__ unsigned int s_bucket;
    __shared__ int s_eqcount;
    __shared__ int s_eqlist[EQ_CAP];
    __shared__ float s_q0[3];
    __shared__ int s_last;
    __shared__ unsigned int s_minIdx;

    const float vx = veh[b * 3 + 0], vy = veh[b * 3 + 1], vz = veh[b * 3 + 2];

    if (tid == 0) { s_minPacked = ~0ull; s_rem = KTOP; s_eqcount = 0; }
    for (int i = tid; i < 256; i += BLOCK) hist[i] = 0;
    for (int i = tid; i < NPART; i += BLOCK) hist32[i] = 0;
    __syncthreads();

    // ---- pass 0: histogram of key bits [31:24] + stable argmin ----
    unsigned long long lmin = ~0ull;
    for (int j = tid; j < nfus; j += BLOCK) {
        float fx = fus[j * 3], fy = fus[j * 3 + 1], fz = fus[j * 3 + 2];
        unsigned int key = __float_as_uint(d2_ref(vx, vy, vz, fx, fy, fz));
        atomicAdd(&hist[key >> 24], 1u);
        unsigned long long p = ((unsigned long long)key << 32) | (unsigned int)j;
        lmin = (p < lmin) ? p : lmin;
    }
    atomicMin(&s_minPacked, lmin);
    __syncthreads();

    if (tid == 0) {
        unsigned cum = 0, rem = s_rem;
        for (int bb = 0; bb < 256; bb++) {
            unsigned c = hist[bb];
            if (cum + c >= rem) { s_bucket = bb; s_rem = rem - cum; break; }
            cum += c;
        }
    }
    __syncthreads();
    unsigned int prefix = s_bucket << 24;

    // ---- passes 1..3: refine 8 bits each ----
    for (int lvl = 1; lvl < 4; ++lvl) {
        int shift = 24 - 8 * lvl;
        unsigned int mask = 0xFFFFFFFFu << (shift + 8);
        for (int i = tid; i < 256; i += BLOCK) hist[i] = 0;
        __syncthreads();
        for (int j = tid; j < nfus; j += BLOCK) {
            float fx = fus[j * 3], fy = fus[j * 3 + 1], fz = fus[j * 3 + 2];
            unsigned int key = __float_as_uint(d2_ref(vx, vy, vz, fx, fy, fz));
            if ((key & mask) == prefix) atomicAdd(&hist[(key >> shift) & 0xFFu], 1u);
        }
        __syncthreads();
        if (tid == 0) {
            unsigned cum = 0, rem = s_rem;
            for (int bb = 0; bb < 256; bb++) {
                unsigned c = hist[bb];
                if (cum + c >= rem) { s_bucket = bb; s_rem = rem - cum; break; }
                cum += c;
            }
        }
        __syncthreads();
        prefix |= s_bucket << shift;
    }
    const unsigned int t = prefix;   // cutoff key; s_rem = #equal keys to take (lowest idx)

    if (tid == 0) {
        int idx0 = (int)(s_minPacked & 0xFFFFFFFFull);
        s_q0[0] = fus[idx0 * 3]; s_q0[1] = fus[idx0 * 3 + 1]; s_q0[2] = fus[idx0 * 3 + 2];
    }
    __syncthreads();
    const float q0x = s_q0[0], q0y = s_q0[1], q0z = s_q0[2];

    // ---- collection: keys < t selected; keys == t gathered for index-rank tie-break ----
    for (int j = tid; j < nfus; j += BLOCK) {
        float fx = fus[j * 3], fy = fus[j * 3 + 1], fz = fus[j * 3 + 2];
        unsigned int key = __float_as_uint(d2_ref(vx, vy, vz, fx, fy, fz));
        if (key < t) {
            int bin = compute_bin(__fsub_rn(fx, q0x), __fsub_rn(fy, q0y), __fsub_rn(fz, q0z));
            if (bin >= 0 && bin < NPART) atomicAdd(&hist32[bin], 1u);
        } else if (key == t) {
            int pos = atomicAdd(&s_eqcount, 1);
            if (pos < EQ_CAP) s_eqlist[pos] = j;
        }
    }
    __syncthreads();

    const int needed = (int)s_rem;
    const int eqc = s_eqcount;
    if (eqc <= EQ_CAP) {
        // take the `needed` lowest indices among equals (matches stable top_k)
        for (int i = tid; i < eqc; i += BLOCK) {
            int ji = s_eqlist[i];
            int rank = 0;
            for (int k2 = 0; k2 < eqc; k2++) rank += (s_eqlist[k2] < ji) ? 1 : 0;
            if (rank < needed) {
                float fx = fus[ji * 3], fy = fus[ji * 3 + 1], fz = fus[ji * 3 + 2];
                int bin = compute_bin(__fsub_rn(fx, q0x), __fsub_rn(fy, q0y), __fsub_rn(fz, q0z));
                if (bin >= 0 && bin < NPART) atomicAdd(&hist32[bin], 1u);
            }
        }
        __syncthreads();
    } else {
        // pathological overflow fallback: iterative min-index extraction (never expected)
        if (tid == 0) s_last = -1;
        __syncthreads();
        for (int it = 0; it < needed; ++it) {
            if (tid == 0) s_minIdx = 0xFFFFFFFFu;
            __syncthreads();
            int last = s_last;
            for (int j = tid; j < nfus; j += BLOCK) {
                float fx = fus[j * 3], fy = fus[j * 3 + 1], fz = fus[j * 3 + 2];
                unsigned int key = __float_as_uint(d2_ref(vx, vy, vz, fx, fy, fz));
                if (key == t && j > last) atomicMin(&s_minIdx, (unsigned)j);
            }
            __syncthreads();
            if (tid == 0) {
                int jm = (int)s_minIdx;
                float fx = fus[jm * 3], fy = fus[jm * 3 + 1], fz = fus[jm * 3 + 2];
                int bin = compute_bin(__fsub_rn(fx, q0x), __fsub_rn(fy, q0y), __fsub_rn(fz, q0z));
                if (bin >= 0 && bin < NPART) hist32[bin] += 1u;
                s_last = jm;
            }
            __syncthreads();
        }
    }

    // ---- epilogue: counts+1 -> L2-normalize*4 -> softmax ----
    if (tid == 0) {
        float counts[NPART], pip[NPART], e[NPART];
        float ss = 0.f;
        for (int p = 0; p < NPART; p++) {
            float c = (float)hist32[p] + 1.0f;
            counts[p] = c;
            ss += c * c;
        }
        float nrm = sqrtf(ss);
        float m = -1e30f;
        for (int p = 0; p < NPART; p++) {
            float v = (counts[p] / nrm) * 4.0f;
            pip[p] = v;
            if (v > m) m = v;
        }
        float sum = 0.f;
        for (int p = 0; p < NPART; p++) { e[p] = expf(pip[p] - m); sum += e[p]; }
        float* o = out + b * NPART;
        for (int p = 0; p < NPART; p++) o[p] = e[p] / sum;
    }
}

extern "C" void kernel_launch(void* const* d_in, const int* in_sizes, int n_in,
                              void* d_out, int out_size, void* d_ws, size_t ws_size,
                              hipStream_t stream) {
    const float* veh = (const float*)d_in[0];   // (1024, 3)
    const float* fus = (const float*)d_in[1];   // (20000, 3)
    float* out = (float*)d_out;                 // (1024, 32)
    int nveh = in_sizes[0] / 3;
    int nfus = in_sizes[1] / 3;
    shape_context_kernel<<<nveh, BLOCK, 0, stream>>>(veh, fus, out, nfus);
}

// Round 2
// 127.714 us; speedup vs baseline: 1.8982x; 1.8982x over previous
//
#include <hip/hip_runtime.h>
#include <math.h>

#define KTOP 200
#define NPART 32
#define BLOCK 256
#define NHIST 2048
#define CAND_CAP 2048

// d2 exactly as numpy: ((dx*dx + dy*dy) + dz*dz), no fma contraction
__device__ __forceinline__ float d2_ref(float ax, float ay, float az,
                                        float bx, float by, float bz) {
    float dx = __fsub_rn(ax, bx), dy = __fsub_rn(ay, by), dz = __fsub_rn(az, bz);
    return __fadd_rn(__fadd_rn(__fmul_rn(dx, dx), __fmul_rn(dy, dy)), __fmul_rn(dz, dz));
}

// shape-context bin of rel = p_j - q0, mirroring the reference f32 math
__device__ __forceinline__ int compute_bin(float rx, float ry, float rz) {
    const float TWO_PI_F = (float)6.283185307179586;
    const float PI_F     = (float)3.141592653589793;
    const float XY_W     = (float)(6.283185307179586 / 4.0);
    const float ZY_W     = (float)(3.141592653589793 / 4.0);

    float d2 = __fadd_rn(__fadd_rn(__fmul_rn(rx, rx), __fmul_rn(ry, ry)), __fmul_rn(rz, rz));
    float D  = sqrtf(__fadd_rn(d2, 1e-7f));
    float dist_bin;
    if (D >= 4.0f)      dist_bin = 1.0f;
    else if (D >= 1.0f) dist_bin = 0.0f;
    else                return -1;

    float axy = fmodf(atan2f(ry, rx) + TWO_PI_F, TWO_PI_F);
    float azy = fmodf(atan2f(ry, rz) + TWO_PI_F, PI_F);
    float xyb = floorf(__fdiv_rn(axy, XY_W));
    float zyb = floorf(__fdiv_rn(azy, ZY_W));
    if (!(xyb >= 0.0f && zyb >= 0.0f)) return -1;
    float ab  = xyb * 4.0f + zyb;
    int bin = (int)(dist_bin * 16.0f + ab);
    return bin;
}

__global__ __launch_bounds__(BLOCK)
void shape_context_kernel(const float* __restrict__ veh,
                          const float* __restrict__ fus,
                          float* __restrict__ out,
                          int nfus) {
    const int b   = blockIdx.x;
    const int tid = threadIdx.x;
    const int lane = tid & 63;
    const int wid  = tid >> 6;

    __shared__ unsigned int hist[NHIST];
    __shared__ unsigned long long cand[CAND_CAP];
    __shared__ unsigned int hist32[NPART];
    __shared__ unsigned int waveTot[BLOCK / 64];
    __shared__ unsigned int waveBase[BLOCK / 64];
    __shared__ unsigned int s_bucket, s_rem, s_bcount;
    __shared__ unsigned long long s_minPacked;
    __shared__ int s_candCount;
    __shared__ float s_q0[3];
    __shared__ unsigned long long s_lowBound;

    const float vx = veh[b * 3 + 0], vy = veh[b * 3 + 1], vz = veh[b * 3 + 2];

    // iterate all points with float4-vectorized loads (stride-3 packing)
    auto for_each_point = [&](auto&& fn) {
        const float4* fus4 = (const float4*)fus;
        int ntrip = nfus >> 2;
        for (int m = tid; m < ntrip; m += BLOCK) {
            float4 A = fus4[3 * m], B4 = fus4[3 * m + 1], C4 = fus4[3 * m + 2];
            fn(4 * m + 0, A.x,  A.y,  A.z);
            fn(4 * m + 1, A.w,  B4.x, B4.y);
            fn(4 * m + 2, B4.z, B4.w, C4.x);
            fn(4 * m + 3, C4.y, C4.z, C4.w);
        }
        for (int j = (nfus & ~3) + tid; j < nfus; j += BLOCK)
            fn(j, fus[3 * j], fus[3 * j + 1], fus[3 * j + 2]);
    };

    // parallel "find bucket where cumulative count crosses rem" over hist[NHIST]
    auto find_bucket = [&](unsigned rem) {
        const int PER = NHIST / BLOCK;  // 8
        int base = tid * PER;
        unsigned p = 0;
        #pragma unroll
        for (int i = 0; i < PER; i++) p += hist[base + i];
        unsigned incl = p;
        #pragma unroll
        for (int d = 1; d < 64; d <<= 1) {
            unsigned n = __shfl_up(incl, d, 64);
            if (lane >= d) incl += n;
        }
        if (lane == 63) waveTot[wid] = incl;
        __syncthreads();
        if (tid == 0) {
            unsigned acc = 0;
            for (int w = 0; w < BLOCK / 64; w++) { waveBase[w] = acc; acc += waveTot[w]; }
        }
        __syncthreads();
        unsigned excl = waveBase[wid] + incl - p;
        if (excl < rem && rem <= excl + p) {
            unsigned cum = excl;
            #pragma unroll
            for (int i = 0; i < PER; i++) {
                unsigned c = hist[base + i];
                if (cum + c >= rem) { s_bucket = base + i; s_rem = rem - cum; s_bcount = c; break; }
                cum += c;
            }
        }
        __syncthreads();
    };

    // ---- init ----
    if (tid == 0) { s_minPacked = ~0ull; s_candCount = 0; }
    for (int i = tid; i < NHIST; i += BLOCK) hist[i] = 0;
    for (int i = tid; i < NPART; i += BLOCK) hist32[i] = 0;
    __syncthreads();

    // ---- scan A: coarse histogram (key>>21) + stable argmin ----
    unsigned long long lmin = ~0ull;
    for_each_point([&](int j, float fx, float fy, float fz) {
        unsigned key = __float_as_uint(d2_ref(vx, vy, vz, fx, fy, fz));
        atomicAdd(&hist[key >> 21], 1u);
        unsigned long long p = ((unsigned long long)key << 32) | (unsigned)j;
        lmin = (p < lmin) ? p : lmin;
    });
    #pragma unroll
    for (int d = 32; d > 0; d >>= 1) {
        unsigned long long o = __shfl_xor(lmin, d, 64);
        lmin = (o < lmin) ? o : lmin;
    }
    if (lane == 0) atomicMin(&s_minPacked, lmin);
    __syncthreads();

    find_bucket(KTOP);
    unsigned T = s_bucket;
    unsigned rem = s_rem;
    unsigned bcount = s_bcount;
    int shift = 21;

    if (tid == 0) {
        int idx0 = (int)(s_minPacked & 0xFFFFFFFFull);
        s_q0[0] = fus[idx0 * 3]; s_q0[1] = fus[idx0 * 3 + 1]; s_q0[2] = fus[idx0 * 3 + 2];
    }
    __syncthreads();
    const float q0x = s_q0[0], q0y = s_q0[1], q0z = s_q0[2];

    // ---- rare: refine threshold bucket if too many candidates ----
    while (bcount > CAND_CAP && shift > 0) {
        int newshift = (shift > 11) ? (shift - 11) : 0;
        unsigned digmask = (1u << (shift - newshift)) - 1;
        for (int i = tid; i < NHIST; i += BLOCK) hist[i] = 0;
        __syncthreads();
        for_each_point([&](int j, float fx, float fy, float fz) {
            unsigned key = __float_as_uint(d2_ref(vx, vy, vz, fx, fy, fz));
            if ((key >> shift) == T) atomicAdd(&hist[(key >> newshift) & digmask], 1u);
        });
        __syncthreads();
        find_bucket(rem);
        T = (T << (shift - newshift)) | s_bucket;
        rem = s_rem;
        bcount = s_bcount;
        shift = newshift;
    }

    // ---- scan B: classify; definite winners -> bins, boundary bucket -> candidate list ----
    for_each_point([&](int j, float fx, float fy, float fz) {
        unsigned key = __float_as_uint(d2_ref(vx, vy, vz, fx, fy, fz));
        unsigned hi = key >> shift;
        if (hi < T) {
            int bin = compute_bin(__fsub_rn(fx, q0x), __fsub_rn(fy, q0y), __fsub_rn(fz, q0z));
            if (bin >= 0 && bin < NPART) atomicAdd(&hist32[bin], 1u);
        } else if (hi == T) {
            int pos = atomicAdd(&s_candCount, 1);
            if (pos < CAND_CAP) cand[pos] = ((unsigned long long)key << 32) | (unsigned)j;
        }
    });
    __syncthreads();

    int cnt = s_candCount;
    if (cnt <= CAND_CAP) {
        // exact stable ranking among candidates by (key, idx)
        for (int i = tid; i < cnt; i += BLOCK) {
            unsigned long long me = cand[i];
            int rank = 0;
            for (int k2 = 0; k2 < cnt; k2++) rank += (cand[k2] < me) ? 1 : 0;
            if (rank < (int)rem) {
                int ji = (int)(me & 0xFFFFFFFFull);
                float fx = fus[ji * 3], fy = fus[ji * 3 + 1], fz = fus[ji * 3 + 2];
                int bin = compute_bin(__fsub_rn(fx, q0x), __fsub_rn(fy, q0y), __fsub_rn(fz, q0z));
                if (bin >= 0 && bin < NPART) atomicAdd(&hist32[bin], 1u);
            }
        }
        __syncthreads();
    } else {
        // pathological overflow: serial extraction of `rem` smallest packed (key,idx)
        if (tid == 0) s_lowBound = 0;
        __syncthreads();
        for (unsigned it = 0; it < rem; ++it) {
            if (tid == 0) s_minPacked = ~0ull;
            __syncthreads();
            unsigned long long lowB = s_lowBound;
            unsigned long long lm = ~0ull;
            for_each_point([&](int j, float fx, float fy, float fz) {
                unsigned key = __float_as_uint(d2_ref(vx, vy, vz, fx, fy, fz));
                if ((key >> shift) == T) {
                    unsigned long long p = ((unsigned long long)key << 32) | (unsigned)j;
                    if (p >= lowB && p < lm) lm = p;
                }
            });
            #pragma unroll
            for (int d = 32; d > 0; d >>= 1) {
                unsigned long long o = __shfl_xor(lm, d, 64);
                lm = (o < lm) ? o : lm;
            }
            if (lane == 0) atomicMin(&s_minPacked, lm);
            __syncthreads();
            if (tid == 0) {
                int jm = (int)(s_minPacked & 0xFFFFFFFFull);
                float fx = fus[jm * 3], fy = fus[jm * 3 + 1], fz = fus[jm * 3 + 2];
                int bin = compute_bin(__fsub_rn(fx, q0x), __fsub_rn(fy, q0y), __fsub_rn(fz, q0z));
                if (bin >= 0 && bin < NPART) hist32[bin] += 1u;
                s_lowBound = s_minPacked + 1;
            }
            __syncthreads();
        }
    }

    // ---- epilogue: counts+1 -> L2-normalize*4 -> softmax ----
    if (tid == 0) {
        float counts[NPART], pip[NPART], e[NPART];
        float ss = 0.f;
        for (int p = 0; p < NPART; p++) {
            float c = (float)hist32[p] + 1.0f;
            counts[p] = c;
            ss += c * c;
        }
        float nrm = sqrtf(ss);
        float m = -1e30f;
        for (int p = 0; p < NPART; p++) {
            float v = (counts[p] / nrm) * 4.0f;
            pip[p] = v;
            if (v > m) m = v;
        }
        float sum = 0.f;
        for (int p = 0; p < NPART; p++) { e[p] = expf(pip[p] - m); sum += e[p]; }
        float* o = out + b * NPART;
        for (int p = 0; p < NPART; p++) o[p] = e[p] / sum;
    }
}

extern "C" void kernel_launch(void* const* d_in, const int* in_sizes, int n_in,
                              void* d_out, int out_size, void* d_ws, size_t ws_size,
                              hipStream_t stream) {
    const float* veh = (const float*)d_in[0];   // (1024, 3)
    const float* fus = (const float*)d_in[1];   // (20000, 3)
    float* out = (float*)d_out;                 // (1024, 32)
    int nveh = in_sizes[0] / 3;
    int nfus = in_sizes[1] / 3;
    shape_context_kernel<<<nveh, BLOCK, 0, stream>>>(veh, fus, out, nfus);
}

// Round 3
// 89.197 us; speedup vs baseline: 2.7179x; 1.4318x over previous
//
#include <hip/hip_runtime.h>
#include <math.h>

#define KTOP 200
#define NPART 32
#define BLOCK 512
#define NHIST 2048
#define CAND_CAP 1024
#define WCAP 512
#define MAXIT 10   // register-cached trips: covers nfus <= 4*BLOCK*MAXIT = 20480

// d2 exactly as numpy: ((dx*dx + dy*dy) + dz*dz), no fma contraction
__device__ __forceinline__ float d2_ref(float ax, float ay, float az,
                                        float bx, float by, float bz) {
    float dx = __fsub_rn(ax, bx), dy = __fsub_rn(ay, by), dz = __fsub_rn(az, bz);
    return __fadd_rn(__fadd_rn(__fmul_rn(dx, dx), __fmul_rn(dy, dy)), __fmul_rn(dz, dz));
}

__device__ __forceinline__ unsigned key_of(const float* __restrict__ fus, int j,
                                           float vx, float vy, float vz) {
    return __float_as_uint(d2_ref(vx, vy, vz, fus[3*j], fus[3*j+1], fus[3*j+2]));
}

// shape-context bin of rel = p_j - q0, mirroring the reference f32 math
__device__ __forceinline__ int compute_bin(float rx, float ry, float rz) {
    const float TWO_PI_F = (float)6.283185307179586;
    const float PI_F     = (float)3.141592653589793;
    const float XY_W     = (float)(6.283185307179586 / 4.0);
    const float ZY_W     = (float)(3.141592653589793 / 4.0);

    float d2 = __fadd_rn(__fadd_rn(__fmul_rn(rx, rx), __fmul_rn(ry, ry)), __fmul_rn(rz, rz));
    float D  = sqrtf(__fadd_rn(d2, 1e-7f));
    float dist_bin;
    if (D >= 4.0f)      dist_bin = 1.0f;
    else if (D >= 1.0f) dist_bin = 0.0f;
    else                return -1;

    float axy = fmodf(atan2f(ry, rx) + TWO_PI_F, TWO_PI_F);
    float azy = fmodf(atan2f(ry, rz) + TWO_PI_F, PI_F);
    float xyb = floorf(__fdiv_rn(axy, XY_W));
    float zyb = floorf(__fdiv_rn(azy, ZY_W));
    if (!(xyb >= 0.0f && zyb >= 0.0f)) return -1;
    float ab  = xyb * 4.0f + zyb;
    int bin = (int)(dist_bin * 16.0f + ab);
    return bin;
}

__global__ __launch_bounds__(BLOCK, 4)
void shape_context_kernel(const float* __restrict__ veh,
                          const float* __restrict__ fus,
                          float* __restrict__ out,
                          int nfus) {
    const int b   = blockIdx.x;
    const int tid = threadIdx.x;
    const int lane = tid & 63;
    const int wid  = tid >> 6;

    __shared__ unsigned int hist[NHIST];
    __shared__ unsigned long long cand[CAND_CAP];
    __shared__ int wlist[WCAP];
    __shared__ unsigned int hist32[NPART];
    __shared__ unsigned int waveTot[BLOCK / 64];
    __shared__ unsigned int waveBase[BLOCK / 64];
    __shared__ unsigned int s_bucket, s_rem, s_bcount;
    __shared__ unsigned int s_minKey, s_minIdx;
    __shared__ int s_candCount, s_wcount;
    __shared__ float s_q0[3];
    __shared__ unsigned long long s_minPacked, s_lowBound;

    const float vx = veh[b * 3 + 0], vy = veh[b * 3 + 1], vz = veh[b * 3 + 2];
    const float4* fus4 = (const float4*)fus;
    const int ntrip = nfus >> 2;

    if (tid == 0) {
        s_minKey = 0xFFFFFFFFu; s_minIdx = 0xFFFFFFFFu;
        s_candCount = 0; s_wcount = 0;
    }
    for (int i = tid; i < NHIST; i += BLOCK) hist[i] = 0;
    if (tid < NPART) hist32[tid] = 0;
    __syncthreads();

    // parallel "find bucket where cumulative count crosses rem" over hist[NHIST]
    auto find_bucket = [&](unsigned remq) {
        const int PER = NHIST / BLOCK;  // 4
        int base = tid * PER;
        unsigned p = 0;
        #pragma unroll
        for (int i = 0; i < PER; i++) p += hist[base + i];
        unsigned incl = p;
        #pragma unroll
        for (int d = 1; d < 64; d <<= 1) {
            unsigned n = __shfl_up(incl, d, 64);
            if (lane >= d) incl += n;
        }
        if (lane == 63) waveTot[wid] = incl;
        __syncthreads();
        if (tid == 0) {
            unsigned acc = 0;
            for (int w = 0; w < BLOCK / 64; w++) { waveBase[w] = acc; acc += waveTot[w]; }
        }
        __syncthreads();
        unsigned excl = waveBase[wid] + incl - p;
        if (excl < remq && remq <= excl + p) {
            unsigned cum = excl;
            #pragma unroll
            for (int i = 0; i < PER; i++) {
                unsigned c = hist[base + i];
                if (cum + c >= remq) { s_bucket = base + i; s_rem = remq - cum; s_bcount = c; break; }
                cum += c;
            }
        }
        __syncthreads();
    };

    // ---- scan A: compute keys into registers, coarse histogram, min key ----
    unsigned kreg[MAXIT][4];
    unsigned lmin = 0xFFFFFFFFu;
    #pragma unroll
    for (int it = 0; it < MAXIT; ++it) {
        int m = tid + it * BLOCK;
        if (m < ntrip) {
            float4 A = fus4[3 * m], Bq = fus4[3 * m + 1], Cq = fus4[3 * m + 2];
            float px0 = A.x,  py0 = A.y,  pz0 = A.z;
            float px1 = A.w,  py1 = Bq.x, pz1 = Bq.y;
            float px2 = Bq.z, py2 = Bq.w, pz2 = Cq.x;
            float px3 = Cq.y, py3 = Cq.z, pz3 = Cq.w;
            unsigned k0 = __float_as_uint(d2_ref(vx, vy, vz, px0, py0, pz0));
            unsigned k1 = __float_as_uint(d2_ref(vx, vy, vz, px1, py1, pz1));
            unsigned k2 = __float_as_uint(d2_ref(vx, vy, vz, px2, py2, pz2));
            unsigned k3 = __float_as_uint(d2_ref(vx, vy, vz, px3, py3, pz3));
            kreg[it][0] = k0; kreg[it][1] = k1; kreg[it][2] = k2; kreg[it][3] = k3;
            atomicAdd(&hist[k0 >> 21], 1u);
            atomicAdd(&hist[k1 >> 21], 1u);
            atomicAdd(&hist[k2 >> 21], 1u);
            atomicAdd(&hist[k3 >> 21], 1u);
            lmin = min(lmin, min(min(k0, k1), min(k2, k3)));
        } else {
            kreg[it][0] = kreg[it][1] = kreg[it][2] = kreg[it][3] = 0xFFFFFFFFu;
        }
    }
    // streaming extras (only if nfus > 4*BLOCK*MAXIT or nfus % 4 != 0)
    for (int m = MAXIT * BLOCK + tid; m < ntrip; m += BLOCK) {
        #pragma unroll
        for (int q = 0; q < 4; ++q) {
            unsigned k = key_of(fus, 4 * m + q, vx, vy, vz);
            atomicAdd(&hist[k >> 21], 1u);
            lmin = min(lmin, k);
        }
    }
    for (int j = (nfus & ~3) + tid; j < nfus; j += BLOCK) {
        unsigned k = key_of(fus, j, vx, vy, vz);
        atomicAdd(&hist[k >> 21], 1u);
        lmin = min(lmin, k);
    }
    #pragma unroll
    for (int d = 32; d > 0; d >>= 1) lmin = min(lmin, __shfl_xor(lmin, d, 64));
    if (lane == 0) atomicMin(&s_minKey, lmin);
    __syncthreads();

    // ---- stable argmin: lowest index among keys equal to min key ----
    const unsigned mk = s_minKey;
    #pragma unroll
    for (int it = 0; it < MAXIT; ++it) {
        int m = tid + it * BLOCK;
        if (m < ntrip) {
            #pragma unroll
            for (int q = 0; q < 4; ++q)
                if (kreg[it][q] == mk) atomicMin(&s_minIdx, (unsigned)(4 * m + q));
        }
    }
    for (int m = MAXIT * BLOCK + tid; m < ntrip; m += BLOCK)
        #pragma unroll
        for (int q = 0; q < 4; ++q)
            if (key_of(fus, 4 * m + q, vx, vy, vz) == mk) atomicMin(&s_minIdx, (unsigned)(4 * m + q));
    for (int j = (nfus & ~3) + tid; j < nfus; j += BLOCK)
        if (key_of(fus, j, vx, vy, vz) == mk) atomicMin(&s_minIdx, (unsigned)j);

    find_bucket(KTOP);
    unsigned T = s_bucket;
    unsigned rem = s_rem;
    unsigned bcount = s_bcount;
    int shift = 21;

    if (tid == 0) {
        int idx0 = (int)s_minIdx;
        s_q0[0] = fus[idx0 * 3]; s_q0[1] = fus[idx0 * 3 + 1]; s_q0[2] = fus[idx0 * 3 + 2];
    }
    __syncthreads();
    const float q0x = s_q0[0], q0y = s_q0[1], q0z = s_q0[2];

    // ---- rare: refine threshold bucket if too many candidates ----
    while (bcount > CAND_CAP && shift > 0) {
        int newshift = (shift > 11) ? (shift - 11) : 0;
        unsigned digmask = (1u << (shift - newshift)) - 1;
        for (int i = tid; i < NHIST; i += BLOCK) hist[i] = 0;
        __syncthreads();
        #pragma unroll
        for (int it = 0; it < MAXIT; ++it) {
            int m = tid + it * BLOCK;
            if (m < ntrip) {
                #pragma unroll
                for (int q = 0; q < 4; ++q) {
                    unsigned k = kreg[it][q];
                    if ((k >> shift) == T) atomicAdd(&hist[(k >> newshift) & digmask], 1u);
                }
            }
        }
        for (int m = MAXIT * BLOCK + tid; m < ntrip; m += BLOCK)
            #pragma unroll
            for (int q = 0; q < 4; ++q) {
                unsigned k = key_of(fus, 4 * m + q, vx, vy, vz);
                if ((k >> shift) == T) atomicAdd(&hist[(k >> newshift) & digmask], 1u);
            }
        for (int j = (nfus & ~3) + tid; j < nfus; j += BLOCK) {
            unsigned k = key_of(fus, j, vx, vy, vz);
            if ((k >> shift) == T) atomicAdd(&hist[(k >> newshift) & digmask], 1u);
        }
        __syncthreads();
        find_bucket(rem);
        T = (T << (shift - newshift)) | s_bucket;
        rem = s_rem;
        bcount = s_bcount;
        shift = newshift;
    }

    // ---- scan B (registers): winners -> wlist, boundary bucket -> cand ----
    #pragma unroll
    for (int it = 0; it < MAXIT; ++it) {
        int m = tid + it * BLOCK;
        if (m < ntrip) {
            #pragma unroll
            for (int q = 0; q < 4; ++q) {
                unsigned k = kreg[it][q];
                unsigned hi = k >> shift;
                if (hi < T) {
                    int pos = atomicAdd(&s_wcount, 1);
                    if (pos < WCAP) wlist[pos] = 4 * m + q;
                } else if (hi == T) {
                    int pos = atomicAdd(&s_candCount, 1);
                    if (pos < CAND_CAP) cand[pos] = ((unsigned long long)k << 32) | (unsigned)(4 * m + q);
                }
            }
        }
    }
    for (int m = MAXIT * BLOCK + tid; m < ntrip; m += BLOCK)
        #pragma unroll
        for (int q = 0; q < 4; ++q) {
            unsigned k = key_of(fus, 4 * m + q, vx, vy, vz);
            unsigned hi = k >> shift;
            if (hi < T) { int pos = atomicAdd(&s_wcount, 1); if (pos < WCAP) wlist[pos] = 4 * m + q; }
            else if (hi == T) { int pos = atomicAdd(&s_candCount, 1); if (pos < CAND_CAP) cand[pos] = ((unsigned long long)k << 32) | (unsigned)(4 * m + q); }
        }
    for (int j = (nfus & ~3) + tid; j < nfus; j += BLOCK) {
        unsigned k = key_of(fus, j, vx, vy, vz);
        unsigned hi = k >> shift;
        if (hi < T) { int pos = atomicAdd(&s_wcount, 1); if (pos < WCAP) wlist[pos] = j; }
        else if (hi == T) { int pos = atomicAdd(&s_candCount, 1); if (pos < CAND_CAP) cand[pos] = ((unsigned long long)k << 32) | (unsigned)j; }
    }
    __syncthreads();

    const int cnt = s_candCount;
    if (cnt <= CAND_CAP) {
        // exact stable ranking among boundary candidates by (key, idx); qualifiers join wlist
        for (int i = tid; i < cnt; i += BLOCK) {
            unsigned long long me = cand[i];
            int rank = 0;
            for (int k2 = 0; k2 < cnt; k2++) rank += (cand[k2] < me) ? 1 : 0;
            if (rank < (int)rem) {
                int pos = atomicAdd(&s_wcount, 1);
                if (pos < WCAP) wlist[pos] = (int)(me & 0xFFFFFFFFull);
            }
        }
    }
    __syncthreads();

    // ---- compact winner processing: one compute_bin per thread, no divergence waste ----
    {
        int wc = s_wcount; if (wc > WCAP) wc = WCAP;
        for (int i = tid; i < wc; i += BLOCK) {
            int j = wlist[i];
            float fx = fus[3 * j], fy = fus[3 * j + 1], fz = fus[3 * j + 2];
            int bin = compute_bin(__fsub_rn(fx, q0x), __fsub_rn(fy, q0y), __fsub_rn(fz, q0z));
            if (bin >= 0 && bin < NPART) atomicAdd(&hist32[bin], 1u);
        }
    }
    __syncthreads();

    if (cnt > CAND_CAP) {
        // pathological fallback: serial extraction of `rem` smallest packed (key,idx) in bucket T
        if (tid == 0) s_lowBound = 0;
        __syncthreads();
        for (unsigned itx = 0; itx < rem; ++itx) {
            if (tid == 0) s_minPacked = ~0ull;
            __syncthreads();
            unsigned long long lowB = s_lowBound;
            unsigned long long lm = ~0ull;
            for (int j = tid; j < nfus; j += BLOCK) {
                unsigned k = key_of(fus, j, vx, vy, vz);
                if ((k >> shift) == T) {
                    unsigned long long p = ((unsigned long long)k << 32) | (unsigned)j;
                    if (p >= lowB && p < lm) lm = p;
                }
            }
            #pragma unroll
            for (int d = 32; d > 0; d >>= 1) {
                unsigned long long o = __shfl_xor(lm, d, 64);
                lm = (o < lm) ? o : lm;
            }
            if (lane == 0) atomicMin(&s_minPacked, lm);
            __syncthreads();
            if (tid == 0) {
                int jm = (int)(s_minPacked & 0xFFFFFFFFull);
                float fx = fus[jm * 3], fy = fus[jm * 3 + 1], fz = fus[jm * 3 + 2];
                int bin = compute_bin(__fsub_rn(fx, q0x), __fsub_rn(fy, q0y), __fsub_rn(fz, q0z));
                if (bin >= 0 && bin < NPART) hist32[bin] += 1u;
                s_lowBound = s_minPacked + 1;
            }
            __syncthreads();
        }
    }

    // ---- epilogue (32 lanes of wave 0): counts+1 -> L2-normalize*4 -> softmax ----
    if (tid < NPART) {
        float c = (float)hist32[tid] + 1.0f;
        float ss = __fmul_rn(c, c);
        #pragma unroll
        for (int d = 16; d > 0; d >>= 1) ss += __shfl_xor(ss, d, 64);
        float v = __fmul_rn(__fdiv_rn(c, sqrtf(ss)), 4.0f);
        float mx = v;
        #pragma unroll
        for (int d = 16; d > 0; d >>= 1) mx = fmaxf(mx, __shfl_xor(mx, d, 64));
        float e = expf(v - mx);
        float sum = e;
        #pragma unroll
        for (int d = 16; d > 0; d >>= 1) sum += __shfl_xor(sum, d, 64);
        out[b * NPART + tid] = __fdiv_rn(e, sum);
    }
}

extern "C" void kernel_launch(void* const* d_in, const int* in_sizes, int n_in,
                              void* d_out, int out_size, void* d_ws, size_t ws_size,
                              hipStream_t stream) {
    const float* veh = (const float*)d_in[0];   // (1024, 3)
    const float* fus = (const float*)d_in[1];   // (20000, 3)
    float* out = (float*)d_out;                 // (1024, 32)
    int nveh = in_sizes[0] / 3;
    int nfus = in_sizes[1] / 3;
    shape_context_kernel<<<nveh, BLOCK, 0, stream>>>(veh, fus, out, nfus);
}

// Round 4
// 82.679 us; speedup vs baseline: 2.9322x; 1.0788x over previous
//
#include <hip/hip_runtime.h>
#include <math.h>

#define KTOP 200
#define NPART 32
#define BLOCK 512
#define NHIST 2048
#define CAND_CAP 512
#define WCAP 512
#define MAXIT 10   // cached trips cover nfus <= 4*BLOCK*MAXIT = 20480

// d2 exactly as numpy: ((dx*dx + dy*dy) + dz*dz), no fma contraction
__device__ __forceinline__ float d2_ref(float ax, float ay, float az,
                                        float bx, float by, float bz) {
    float dx = __fsub_rn(ax, bx), dy = __fsub_rn(ay, by), dz = __fsub_rn(az, bz);
    return __fadd_rn(__fadd_rn(__fmul_rn(dx, dx), __fmul_rn(dy, dy)), __fmul_rn(dz, dz));
}

__device__ __forceinline__ unsigned key_of(const float* __restrict__ fus, int j,
                                           float vx, float vy, float vz) {
    return __float_as_uint(d2_ref(vx, vy, vz, fus[3*j], fus[3*j+1], fus[3*j+2]));
}

// shape-context bin of rel = p_j - q0, mirroring the reference f32 math
__device__ __forceinline__ int compute_bin(float rx, float ry, float rz) {
    const float TWO_PI_F = (float)6.283185307179586;
    const float PI_F     = (float)3.141592653589793;
    const float XY_W     = (float)(6.283185307179586 / 4.0);
    const float ZY_W     = (float)(3.141592653589793 / 4.0);

    float d2 = __fadd_rn(__fadd_rn(__fmul_rn(rx, rx), __fmul_rn(ry, ry)), __fmul_rn(rz, rz));
    float D  = sqrtf(__fadd_rn(d2, 1e-7f));
    float dist_bin;
    if (D >= 4.0f)      dist_bin = 1.0f;
    else if (D >= 1.0f) dist_bin = 0.0f;
    else                return -1;

    float axy = fmodf(atan2f(ry, rx) + TWO_PI_F, TWO_PI_F);
    float azy = fmodf(atan2f(ry, rz) + TWO_PI_F, PI_F);
    float xyb = floorf(__fdiv_rn(axy, XY_W));
    float zyb = floorf(__fdiv_rn(azy, ZY_W));
    if (!(xyb >= 0.0f && zyb >= 0.0f)) return -1;
    float ab  = xyb * 4.0f + zyb;
    int bin = (int)(dist_bin * 16.0f + ab);
    return bin;
}

__global__ __launch_bounds__(BLOCK, 8)
void shape_context_kernel(const float* __restrict__ veh,
                          const float* __restrict__ fus,
                          float* __restrict__ out,
                          int nfus) {
    const int b   = blockIdx.x;
    const int tid = threadIdx.x;
    const int lane = tid & 63;
    const int wid  = tid >> 6;

    __shared__ unsigned int hist[NHIST];
    __shared__ unsigned long long cand[CAND_CAP];
    __shared__ int wlist[WCAP];
    __shared__ unsigned int hist32[NPART];
    __shared__ unsigned int waveTot[BLOCK / 64];
    __shared__ unsigned int waveBase[BLOCK / 64];
    __shared__ unsigned int s_bucket, s_rem, s_bcount;
    __shared__ int s_candCount, s_wcount;
    __shared__ float s_q0[3];
    __shared__ unsigned long long s_minPacked, s_lowBound;

    const float vx = veh[b * 3 + 0], vy = veh[b * 3 + 1], vz = veh[b * 3 + 2];
    const float4* fus4 = (const float4*)fus;
    const int ntrip = nfus >> 2;

    if (tid == 0) { s_minPacked = ~0ull; s_candCount = 0; s_wcount = 0; }
    for (int i = tid; i < NHIST; i += BLOCK) hist[i] = 0;
    if (tid < NPART) hist32[tid] = 0;
    __syncthreads();

    // parallel "find bucket where cumulative count crosses rem" over hist[NHIST]
    auto find_bucket = [&](unsigned remq) {
        const int PER = NHIST / BLOCK;  // 4
        int base = tid * PER;
        unsigned p = 0;
        #pragma unroll
        for (int i = 0; i < PER; i++) p += hist[base + i];
        unsigned incl = p;
        #pragma unroll
        for (int d = 1; d < 64; d <<= 1) {
            unsigned n = __shfl_up(incl, d, 64);
            if (lane >= d) incl += n;
        }
        if (lane == 63) waveTot[wid] = incl;
        __syncthreads();
        if (tid == 0) {
            unsigned acc = 0;
            for (int w = 0; w < BLOCK / 64; w++) { waveBase[w] = acc; acc += waveTot[w]; }
        }
        __syncthreads();
        unsigned excl = waveBase[wid] + incl - p;
        if (excl < remq && remq <= excl + p) {
            unsigned cum = excl;
            #pragma unroll
            for (int i = 0; i < PER; i++) {
                unsigned c = hist[base + i];
                if (cum + c >= remq) { s_bucket = base + i; s_rem = remq - cum; s_bcount = c; break; }
                cum += c;
            }
        }
        __syncthreads();
    };

    // ---- scan A: keys -> coarse hist (key>>21); cache 16-bit bucket ids; packed (key,idx) min ----
    unsigned long long khi[MAXIT];     // 4 x 16-bit bucket ids per trip
    unsigned long long lmin = ~0ull;
    #pragma unroll
    for (int it = 0; it < MAXIT; ++it) {
        int m = tid + it * BLOCK;
        if (m < ntrip) {
            float4 A = fus4[3 * m], Bq = fus4[3 * m + 1], Cq = fus4[3 * m + 2];
            unsigned k0 = __float_as_uint(d2_ref(vx, vy, vz, A.x,  A.y,  A.z));
            unsigned k1 = __float_as_uint(d2_ref(vx, vy, vz, A.w,  Bq.x, Bq.y));
            unsigned k2 = __float_as_uint(d2_ref(vx, vy, vz, Bq.z, Bq.w, Cq.x));
            unsigned k3 = __float_as_uint(d2_ref(vx, vy, vz, Cq.y, Cq.z, Cq.w));
            atomicAdd(&hist[k0 >> 21], 1u);
            atomicAdd(&hist[k1 >> 21], 1u);
            atomicAdd(&hist[k2 >> 21], 1u);
            atomicAdd(&hist[k3 >> 21], 1u);
            khi[it] = (unsigned long long)(k0 >> 21)
                    | ((unsigned long long)(k1 >> 21) << 16)
                    | ((unsigned long long)(k2 >> 21) << 32)
                    | ((unsigned long long)(k3 >> 21) << 48);
            unsigned jb = 4 * m;
            unsigned long long p0 = ((unsigned long long)k0 << 32) | (jb + 0);
            unsigned long long p1 = ((unsigned long long)k1 << 32) | (jb + 1);
            unsigned long long p2 = ((unsigned long long)k2 << 32) | (jb + 2);
            unsigned long long p3 = ((unsigned long long)k3 << 32) | (jb + 3);
            unsigned long long pm = min(min(p0, p1), min(p2, p3));
            lmin = min(lmin, pm);
        } else {
            khi[it] = 0xFFFFFFFFFFFFFFFFull;   // sentinel: never < T, never == T
        }
    }
    // streaming extras (nfus > 4*BLOCK*MAXIT or nfus % 4 != 0) — not cached
    for (int m = MAXIT * BLOCK + tid; m < ntrip; m += BLOCK) {
        #pragma unroll
        for (int q = 0; q < 4; ++q) {
            unsigned k = key_of(fus, 4 * m + q, vx, vy, vz);
            atomicAdd(&hist[k >> 21], 1u);
            lmin = min(lmin, ((unsigned long long)k << 32) | (unsigned)(4 * m + q));
        }
    }
    for (int j = (nfus & ~3) + tid; j < nfus; j += BLOCK) {
        unsigned k = key_of(fus, j, vx, vy, vz);
        atomicAdd(&hist[k >> 21], 1u);
        lmin = min(lmin, ((unsigned long long)k << 32) | (unsigned)j);
    }
    #pragma unroll
    for (int d = 32; d > 0; d >>= 1) {
        unsigned long long o = __shfl_xor(lmin, d, 64);
        lmin = (o < lmin) ? o : lmin;
    }
    if (lane == 0) atomicMin(&s_minPacked, lmin);
    __syncthreads();

    find_bucket(KTOP);
    unsigned T = s_bucket;
    unsigned rem = s_rem;
    unsigned bcount = s_bcount;
    int shift = 21;

    if (tid == 0) {
        int idx0 = (int)(s_minPacked & 0xFFFFFFFFull);
        s_q0[0] = fus[idx0 * 3]; s_q0[1] = fus[idx0 * 3 + 1]; s_q0[2] = fus[idx0 * 3 + 2];
    }
    __syncthreads();
    const float q0x = s_q0[0], q0y = s_q0[1], q0z = s_q0[2];

    // ---- rare: refine threshold bucket if too many candidates (reload-based) ----
    while (bcount > CAND_CAP && shift > 0) {
        int newshift = (shift > 11) ? (shift - 11) : 0;
        unsigned digmask = (1u << (shift - newshift)) - 1;
        for (int i = tid; i < NHIST; i += BLOCK) hist[i] = 0;
        __syncthreads();
        for (int j = tid; j < nfus; j += BLOCK) {
            unsigned k = key_of(fus, j, vx, vy, vz);
            if ((k >> shift) == T) atomicAdd(&hist[(k >> newshift) & digmask], 1u);
        }
        __syncthreads();
        find_bucket(rem);
        T = (T << (shift - newshift)) | s_bucket;
        rem = s_rem;
        bcount = s_bcount;
        shift = newshift;
    }

    // ---- scan B: winners -> wlist, boundary bucket -> cand (exact keys recomputed) ----
    if (shift == 21) {
        #pragma unroll
        for (int it = 0; it < MAXIT; ++it) {
            unsigned long long packed = khi[it];
            int jb = 4 * (tid + it * BLOCK);
            #pragma unroll
            for (int q = 0; q < 4; ++q) {
                unsigned hi = (unsigned)((packed >> (16 * q)) & 0xFFFFull);
                if (hi < T) {
                    int pos = atomicAdd(&s_wcount, 1);
                    if (pos < WCAP) wlist[pos] = jb + q;
                } else if (hi == T) {
                    int j = jb + q;
                    unsigned k = key_of(fus, j, vx, vy, vz);
                    int pos = atomicAdd(&s_candCount, 1);
                    if (pos < CAND_CAP) cand[pos] = ((unsigned long long)k << 32) | (unsigned)j;
                }
            }
        }
        for (int m = MAXIT * BLOCK + tid; m < ntrip; m += BLOCK)
            #pragma unroll
            for (int q = 0; q < 4; ++q) {
                int j = 4 * m + q;
                unsigned k = key_of(fus, j, vx, vy, vz);
                unsigned hi = k >> shift;
                if (hi < T) { int pos = atomicAdd(&s_wcount, 1); if (pos < WCAP) wlist[pos] = j; }
                else if (hi == T) { int pos = atomicAdd(&s_candCount, 1); if (pos < CAND_CAP) cand[pos] = ((unsigned long long)k << 32) | (unsigned)j; }
            }
        for (int j = (nfus & ~3) + tid; j < nfus; j += BLOCK) {
            unsigned k = key_of(fus, j, vx, vy, vz);
            unsigned hi = k >> shift;
            if (hi < T) { int pos = atomicAdd(&s_wcount, 1); if (pos < WCAP) wlist[pos] = j; }
            else if (hi == T) { int pos = atomicAdd(&s_candCount, 1); if (pos < CAND_CAP) cand[pos] = ((unsigned long long)k << 32) | (unsigned)j; }
        }
    } else {
        for (int j = tid; j < nfus; j += BLOCK) {
            unsigned k = key_of(fus, j, vx, vy, vz);
            unsigned hi = k >> shift;
            if (hi < T) { int pos = atomicAdd(&s_wcount, 1); if (pos < WCAP) wlist[pos] = j; }
            else if (hi == T) { int pos = atomicAdd(&s_candCount, 1); if (pos < CAND_CAP) cand[pos] = ((unsigned long long)k << 32) | (unsigned)j; }
        }
    }
    __syncthreads();

    const int cnt = s_candCount;
    if (cnt <= CAND_CAP) {
        // exact stable ranking among boundary candidates by (key, idx); qualifiers join wlist
        for (int i = tid; i < cnt; i += BLOCK) {
            unsigned long long me = cand[i];
            int rank = 0;
            for (int k2 = 0; k2 < cnt; k2++) rank += (cand[k2] < me) ? 1 : 0;
            if (rank < (int)rem) {
                int pos = atomicAdd(&s_wcount, 1);
                if (pos < WCAP) wlist[pos] = (int)(me & 0xFFFFFFFFull);
            }
        }
    }
    __syncthreads();

    // ---- compact winner processing: ~one compute_bin per thread ----
    {
        int wc = s_wcount; if (wc > WCAP) wc = WCAP;
        for (int i = tid; i < wc; i += BLOCK) {
            int j = wlist[i];
            float fx = fus[3 * j], fy = fus[3 * j + 1], fz = fus[3 * j + 2];
            int bin = compute_bin(__fsub_rn(fx, q0x), __fsub_rn(fy, q0y), __fsub_rn(fz, q0z));
            if (bin >= 0 && bin < NPART) atomicAdd(&hist32[bin], 1u);
        }
    }
    __syncthreads();

    if (cnt > CAND_CAP) {
        // pathological fallback: serial extraction of `rem` smallest packed (key,idx) in bucket T
        if (tid == 0) s_lowBound = 0;
        __syncthreads();
        for (unsigned itx = 0; itx < rem; ++itx) {
            if (tid == 0) s_minPacked = ~0ull;
            __syncthreads();
            unsigned long long lowB = s_lowBound;
            unsigned long long lm = ~0ull;
            for (int j = tid; j < nfus; j += BLOCK) {
                unsigned k = key_of(fus, j, vx, vy, vz);
                if ((k >> shift) == T) {
                    unsigned long long p = ((unsigned long long)k << 32) | (unsigned)j;
                    if (p >= lowB && p < lm) lm = p;
                }
            }
            #pragma unroll
            for (int d = 32; d > 0; d >>= 1) {
                unsigned long long o = __shfl_xor(lm, d, 64);
                lm = (o < lm) ? o : lm;
            }
            if (lane == 0) atomicMin(&s_minPacked, lm);
            __syncthreads();
            if (tid == 0) {
                int jm = (int)(s_minPacked & 0xFFFFFFFFull);
                float fx = fus[jm * 3], fy = fus[jm * 3 + 1], fz = fus[jm * 3 + 2];
                int bin = compute_bin(__fsub_rn(fx, q0x), __fsub_rn(fy, q0y), __fsub_rn(fz, q0z));
                if (bin >= 0 && bin < NPART) hist32[bin] += 1u;
                s_lowBound = s_minPacked + 1;
            }
            __syncthreads();
        }
    }

    // ---- epilogue (32 lanes of wave 0): counts+1 -> L2-normalize*4 -> softmax ----
    if (tid < NPART) {
        float c = (float)hist32[tid] + 1.0f;
        float ss = __fmul_rn(c, c);
        #pragma unroll
        for (int d = 16; d > 0; d >>= 1) ss += __shfl_xor(ss, d, 64);
        float v = __fmul_rn(__fdiv_rn(c, sqrtf(ss)), 4.0f);
        float mx = v;
        #pragma unroll
        for (int d = 16; d > 0; d >>= 1) mx = fmaxf(mx, __shfl_xor(mx, d, 64));
        float e = expf(v - mx);
        float sum = e;
        #pragma unroll
        for (int d = 16; d > 0; d >>= 1) sum += __shfl_xor(sum, d, 64);
        out[b * NPART + tid] = __fdiv_rn(e, sum);
    }
}

extern "C" void kernel_launch(void* const* d_in, const int* in_sizes, int n_in,
                              void* d_out, int out_size, void* d_ws, size_t ws_size,
                              hipStream_t stream) {
    const float* veh = (const float*)d_in[0];   // (1024, 3)
    const float* fus = (const float*)d_in[1];   // (20000, 3)
    float* out = (float*)d_out;                 // (1024, 32)
    int nveh = in_sizes[0] / 3;
    int nfus = in_sizes[1] / 3;
    shape_context_kernel<<<nveh, BLOCK, 0, stream>>>(veh, fus, out, nfus);
}